// Round 5
// baseline (235.141 us; speedup 1.0000x reference)
//
#include <hip/hip_runtime.h>
#include <math.h>

#define SEQ 2048
#define EMB 1024
#define NH  16
#define HD  64

typedef __attribute__((ext_vector_type(8))) short short8;   // 8 bf16 = 4 VGPRs
typedef __attribute__((ext_vector_type(4))) float f32x4;    // MFMA acc

static const size_t XE = (size_t)2 * SEQ * EMB;  // 4,194,304 elems

// RNE float -> bf16 bits (inputs finite)
static __device__ __forceinline__ short f2bf(float f) {
    unsigned u = __builtin_bit_cast(unsigned, f);
    u = u + 0x7fffu + ((u >> 16) & 1u);
    return (short)(u >> 16);
}

// packed 2x f32 -> 2x bf16 (low = a, high = b)
#if __has_builtin(__builtin_amdgcn_cvt_pk_bf16_f32)
typedef __attribute__((ext_vector_type(2))) __bf16 bf16x2;
static __device__ __forceinline__ unsigned pk2(float a, float b) {
    bf16x2 v = __builtin_amdgcn_cvt_pk_bf16_f32(a, b);
    return __builtin_bit_cast(unsigned, v);
}
#else
static __device__ __forceinline__ unsigned pk2(float a, float b) {
    return (unsigned)(unsigned short)f2bf(a) |
           ((unsigned)(unsigned short)f2bf(b) << 16);
}
#endif

static __device__ __forceinline__ short8 cvt8(float4 a, float4 b) {
    union { unsigned u[4]; short8 s; } r;
    r.u[0] = pk2(a.x, a.y); r.u[1] = pk2(a.z, a.w);
    r.u[2] = pk2(b.x, b.y); r.u[3] = pk2(b.z, b.w);
    return r.s;
}

// async global->LDS, 16B/lane; LDS dest = wave-uniform base + lane*16
static __device__ __forceinline__ void gload16(const short* g, short8* l) {
    __builtin_amdgcn_global_load_lds(
        (const __attribute__((address_space(1))) void*)g,
        (__attribute__((address_space(3))) void*)l, 16, 0, 0);
}

// Swizzled decode: 768 blocks. xcd = L%8 (round-robin heuristic, locality
// only). Each XCD owns 4 m-strips per z; n-tile cycles inner -> X strip
// (2MB fp32) stays L2-resident.
static __device__ __forceinline__ void proj_decode(
    int L, int& z, int& ty, int& tx) {
    int xcd = L & 7, i = L >> 3;   // i 0..95
    z = i >> 5;                    // 0..2
    int m = i & 31;
    ty = xcd * 4 + (m & 3);        // 0..31
    tx = m >> 2;                   // 0..7
}

// ---------------------------------------------------------------------------
// Projection GEMM: fp32 inputs, inline packed cvt to bf16 in LDS staging,
// register prefetch, LDS double-buffer with ONE barrier/iter, XCD swizzle.
// Tile 128x128, BK=32, 256 thr. z=2 swaps operands (A=Wv, B=values) so the
// output is V^T (vt[b][d][s]) with coalesced stores.
// ---------------------------------------------------------------------------
__global__ __launch_bounds__(256, 3)
void proj_f32(const float* __restrict__ Xq, const float* __restrict__ Xk,
              const float* __restrict__ Xv, const float* __restrict__ Wqm,
              const float* __restrict__ Wkm, const float* __restrict__ Wvm,
              short* __restrict__ qb, short* __restrict__ kbuf,
              short* __restrict__ vt) {
    __shared__ short8 As[2][512];   // 2 x (128 rows x 32 k) = 16KB
    __shared__ short8 Bs[2][512];

    int z, ty, tx;
    proj_decode(blockIdx.x, z, ty, tx);
    const float *Af, *Bf; short* C;
    if (z == 0)      { Af = Xq;  Bf = Wqm; C = qb;   }
    else if (z == 1) { Af = Xk;  Bf = Wkm; C = kbuf; }
    else             { Af = Wvm; Bf = Xv;  C = vt;   }
    const int am0 = (z < 2 ? ty : tx) * 128;
    const int bn0 = (z < 2 ? tx : ty) * 128;

    const int t = threadIdx.x, w = t >> 6, lane = t & 63;
    const int l15 = lane & 15, quad = lane >> 4;
    const int mh = (w >> 1) * 64, nh2 = (w & 1) * 64;

    const int srow = t >> 1;           // 0..127
    const int scp  = (t & 1) << 1;     // chunk pair base: 0 or 2
    const float* pA = Af + (size_t)(am0 + srow) * EMB + scp * 8;
    const float* pB = Bf + (size_t)(bn0 + srow) * EMB + scp * 8;

    f32x4 acc[4][4];
#pragma unroll
    for (int i = 0; i < 4; ++i)
#pragma unroll
        for (int j = 0; j < 4; ++j) acc[i][j] = 0.f;

    float4 a0 = *(const float4*)(pA + 0), a1 = *(const float4*)(pA + 4);
    float4 a2 = *(const float4*)(pA + 8), a3 = *(const float4*)(pA + 12);
    float4 b0 = *(const float4*)(pB + 0), b1 = *(const float4*)(pB + 4);
    float4 b2 = *(const float4*)(pB + 8), b3 = *(const float4*)(pB + 12);

    int p = 0;
    for (int k0 = 0; k0 < EMB; k0 += 32, p ^= 1) {
        As[p][(scp + 0) * 128 + srow] = cvt8(a0, a1);
        As[p][(scp + 1) * 128 + srow] = cvt8(a2, a3);
        Bs[p][(scp + 0) * 128 + srow] = cvt8(b0, b1);
        Bs[p][(scp + 1) * 128 + srow] = cvt8(b2, b3);
        __syncthreads();
        if (k0 + 32 < EMB) {
            const float* nA = pA + k0 + 32;
            const float* nB = pB + k0 + 32;
            a0 = *(const float4*)(nA + 0); a1 = *(const float4*)(nA + 4);
            a2 = *(const float4*)(nA + 8); a3 = *(const float4*)(nA + 12);
            b0 = *(const float4*)(nB + 0); b1 = *(const float4*)(nB + 4);
            b2 = *(const float4*)(nB + 8); b3 = *(const float4*)(nB + 12);
        }
        short8 af[4], bfr[4];
#pragma unroll
        for (int mi = 0; mi < 4; ++mi)
            af[mi] = As[p][quad * 128 + mh + mi * 16 + l15];
#pragma unroll
        for (int ni = 0; ni < 4; ++ni)
            bfr[ni] = Bs[p][quad * 128 + nh2 + ni * 16 + l15];
#pragma unroll
        for (int mi = 0; mi < 4; ++mi)
#pragma unroll
            for (int ni = 0; ni < 4; ++ni)
                acc[mi][ni] = __builtin_amdgcn_mfma_f32_16x16x32_bf16(
                    af[mi], bfr[ni], acc[mi][ni], 0, 0, 0);
    }

#pragma unroll
    for (int mi = 0; mi < 4; ++mi)
#pragma unroll
        for (int ni = 0; ni < 4; ++ni)
#pragma unroll
            for (int r = 0; r < 4; ++r) {
                int gm = am0 + mh + mi * 16 + quad * 4 + r;   // A-row
                int gn = bn0 + nh2 + ni * 16 + l15;           // B-row
                short v = f2bf(acc[mi][ni][r]);
                if (z < 2) {
                    C[(size_t)gm * EMB + gn] = v;             // [m][n]
                } else {  // gm = d, gn = b*2048+s -> vt[b][d][s]
                    C[((size_t)(gn >> 11) * EMB + gm) * SEQ + (gn & 2047)] = v;
                }
            }
}

// ---------------------------------------------------------------------------
// Flash attention, bf16 MFMA, fixed-max softmax, S^T trick. SPLIT-K over the
// key range: fixed-max partials are DIRECTLY addable (no rescale) -- sp=0
// writes unnormalized O into d_out, sp=1 into ws; merge adds + normalizes.
// Ps reuses the Qs LDS region (Q hoisted to regs) -> 48KB -> 3 blocks/CU.
// ---------------------------------------------------------------------------
template <int SPLIT>
__global__ __launch_bounds__(256, 3)
void attn_mfma(const short* __restrict__ Qg, const short* __restrict__ Kg,
               const short* __restrict__ Vtg, float* __restrict__ OutD,
               float* __restrict__ Op1, float* __restrict__ Lg) {
    __shared__ short8 QPs[1024];    // Q [dchunk(8)][qrow(128)], then P 16KB
    __shared__ short8 Ks[2][512];   // dbuf [dchunk(8)][krow(64)] 16KB
    __shared__ short8 Vs[2][512];   // dbuf [kchunk(8)][d(64)]    16KB

    const int t = threadIdx.x, w = t >> 6, lane = t & 63;
    const int l15 = lane & 15, quad = lane >> 4;
    const int L = blockIdx.x;
    const int xcd = L & 7, i = L >> 3;
    const int bh = xcd * 4 + (i & 3);         // 0..31
    const int j = i >> 2;
    const int qt = j & 15, sp = j >> 4;       // sp 0..SPLIT-1
    const int q0 = qt * 128;
    const int b = bh >> 4, h = bh & 15;
    const int KT0 = sp * (SEQ / SPLIT);
    const int NT = (SEQ / SPLIT) / 64;
    const short* Qb = Qg + (size_t)b * SEQ * EMB + h * HD;
    const short* Kb = Kg + (size_t)b * SEQ * EMB + h * HD;
    const short* Vb = Vtg + ((size_t)b * EMB + h * HD) * SEQ;

    // prologue: stage Q tile + K/V tile0
#pragma unroll
    for (int j2 = 0; j2 < 4; ++j2) {
        int g = w * 4 + j2, c = g >> 1, row = (g & 1) * 64 + lane;
        gload16(Qb + (size_t)(q0 + row) * EMB + c * 8, &QPs[g * 64]);
    }
#pragma unroll
    for (int j2 = 0; j2 < 2; ++j2) {
        int c = w * 2 + j2;
        gload16(Kb + (size_t)(KT0 + lane) * EMB + c * 8, &Ks[0][c * 64]);
        gload16(Vb + (size_t)lane * SEQ + KT0 + c * 8, &Vs[0][c * 64]);
    }
    __syncthreads();   // drains prologue loads

    // hoist Q fragments (B-operand, lane l15 = q); Qs LDS dead afterwards
    short8 qf[2][2];
#pragma unroll
    for (int qi = 0; qi < 2; ++qi)
#pragma unroll
        for (int kb2 = 0; kb2 < 2; ++kb2)
            qf[qi][kb2] = QPs[(kb2 * 4 + quad) * 128 + w * 32 + qi * 16 + l15];
    __syncthreads();   // all hoists done before P overwrites QPs

    f32x4 o[2][4];
    float lr[2] = {0.f, 0.f};
#pragma unroll
    for (int qi = 0; qi < 2; ++qi)
#pragma unroll
        for (int ni = 0; ni < 4; ++ni) o[qi][ni] = 0.f;
    const float cl2 = 0.18033688011112042f;   // (1/8) * log2(e)
    const float c0  = 11.541560327111707f;    // 64 * cl2

    int p = 0;
    for (int tt = 0; tt < NT; ++tt, p ^= 1) {
        if (tt) __syncthreads();   // drains buf-p loads (issued last iter)
        if (tt + 1 < NT) {
            int kt = KT0 + (tt + 1) * 64;
#pragma unroll
            for (int j2 = 0; j2 < 2; ++j2) {
                int c = w * 2 + j2;
                gload16(Kb + (size_t)(kt + lane) * EMB + c * 8,
                        &Ks[p ^ 1][c * 64]);
                gload16(Vb + (size_t)lane * SEQ + kt + c * 8,
                        &Vs[p ^ 1][c * 64]);
            }
        }

        // ---- T = K Q^T : rows = key, cols = q ----
        f32x4 s[4][2];
#pragma unroll
        for (int kblk = 0; kblk < 4; ++kblk)
#pragma unroll
            for (int qi = 0; qi < 2; ++qi) s[kblk][qi] = 0.f;
#pragma unroll
        for (int kb2 = 0; kb2 < 2; ++kb2) {
            short8 ak[4];
#pragma unroll
            for (int kblk = 0; kblk < 4; ++kblk)
                ak[kblk] = Ks[p][(kb2 * 4 + quad) * 64 + kblk * 16 + l15];
#pragma unroll
            for (int kblk = 0; kblk < 4; ++kblk)
#pragma unroll
                for (int qi = 0; qi < 2; ++qi)
                    s[kblk][qi] = __builtin_amdgcn_mfma_f32_16x16x32_bf16(
                        ak[kblk], qf[qi][kb2], s[kblk][qi], 0, 0, 0);
        }

        // ---- fixed-max softmax + packed b64 P write (into QPs) ----
#pragma unroll
        for (int qi = 0; qi < 2; ++qi) {
            int row = w * 32 + qi * 16 + l15;
#pragma unroll
            for (int kblk = 0; kblk < 4; ++kblk) {
                float p0 = __builtin_amdgcn_exp2f(fmaf(s[kblk][qi][0], cl2, -c0));
                float p1 = __builtin_amdgcn_exp2f(fmaf(s[kblk][qi][1], cl2, -c0));
                float p2 = __builtin_amdgcn_exp2f(fmaf(s[kblk][qi][2], cl2, -c0));
                float p3 = __builtin_amdgcn_exp2f(fmaf(s[kblk][qi][3], cl2, -c0));
                lr[qi] += (p0 + p1) + (p2 + p3);
                uint2 pv; pv.x = pk2(p0, p1); pv.y = pk2(p2, p3);
                int chunk = kblk * 2 + (quad >> 1);
                *(uint2*)((char*)QPs +
                          (((chunk * 128 + row) << 4) | ((quad & 1) << 3))) = pv;
            }
        }
        // no barrier: each wave reads back only its own q rows (w-partitioned)

        // ---- O += P V ----
#pragma unroll
        for (int kb2 = 0; kb2 < 2; ++kb2) {
            short8 ap[2], bv[4];
#pragma unroll
            for (int qi = 0; qi < 2; ++qi)
                ap[qi] = QPs[(kb2 * 4 + quad) * 128 + w * 32 + qi * 16 + l15];
#pragma unroll
            for (int ni = 0; ni < 4; ++ni)
                bv[ni] = Vs[p][(kb2 * 4 + quad) * 64 + ni * 16 + l15];
#pragma unroll
            for (int qi = 0; qi < 2; ++qi)
#pragma unroll
                for (int ni = 0; ni < 4; ++ni)
                    o[qi][ni] = __builtin_amdgcn_mfma_f32_16x16x32_bf16(
                        ap[qi], bv[ni], o[qi][ni], 0, 0, 0);
        }
    }

    // ---- epilogue ----
#pragma unroll
    for (int qi = 0; qi < 2; ++qi) {
        float l = lr[qi];
        l += __shfl_xor(l, 16);
        l += __shfl_xor(l, 32);
        lr[qi] = l;   // full row-sum for this split, replicated across quads
    }
    if (SPLIT == 1) {
#pragma unroll
        for (int qi = 0; qi < 2; ++qi)
#pragma unroll
            for (int r = 0; r < 4; ++r) {
                float inv = 1.0f / __shfl(lr[qi], quad * 4 + r);
                int q = q0 + w * 32 + qi * 16 + quad * 4 + r;
                float* op = OutD + ((size_t)b * SEQ + q) * EMB + h * HD;
#pragma unroll
                for (int ni = 0; ni < 4; ++ni)
                    op[ni * 16 + l15] = o[qi][ni][r] * inv;
            }
    } else {
        float* dst = sp ? Op1 : OutD;
#pragma unroll
        for (int qi = 0; qi < 2; ++qi)
            if (quad == 0)
                Lg[sp * (2 * NH * SEQ) + bh * SEQ + q0 + w * 32 + qi * 16 + l15]
                    = lr[qi];
#pragma unroll
        for (int qi = 0; qi < 2; ++qi)
#pragma unroll
            for (int r = 0; r < 4; ++r) {
                float os = __shfl(lr[qi], quad * 4 + r);  // keep lanes uniform
                (void)os;
                int q = q0 + w * 32 + qi * 16 + quad * 4 + r;
                float* op = dst + ((size_t)b * SEQ + q) * EMB + h * HD;
#pragma unroll
                for (int ni = 0; ni < 4; ++ni)
                    op[ni * 16 + l15] = o[qi][ni][r];
            }
    }
}

// ---------------------------------------------------------------------------
// Merge the two split-K partials: out = (O0 + O1) / (l0 + l1). 8 elems/thr.
// ---------------------------------------------------------------------------
__global__ __launch_bounds__(256)
void merge_split(float* __restrict__ OutD, const float* __restrict__ Op1,
                 const float* __restrict__ Lg) {
    size_t i = ((size_t)blockIdx.x * 256 + threadIdx.x) * 8;
    int e = (int)(i & 1023);
    int q = (int)((i >> 10) & 2047);
    int b = (int)(i >> 21);
    int h = e >> 6;
    int li = (b * NH + h) * SEQ + q;
    float inv = 1.0f / (Lg[li] + Lg[2 * NH * SEQ + li]);
    float4 x0 = *(float4*)(OutD + i), x1 = *(float4*)(OutD + i + 4);
    float4 y0 = *(const float4*)(Op1 + i), y1 = *(const float4*)(Op1 + i + 4);
    x0.x = (x0.x + y0.x) * inv; x0.y = (x0.y + y0.y) * inv;
    x0.z = (x0.z + y0.z) * inv; x0.w = (x0.w + y0.w) * inv;
    x1.x = (x1.x + y1.x) * inv; x1.y = (x1.y + y1.y) * inv;
    x1.z = (x1.z + y1.z) * inv; x1.w = (x1.w + y1.w) * inv;
    *(float4*)(OutD + i) = x0;
    *(float4*)(OutD + i + 4) = x1;
}

// ---------------------------------------------------------------------------
extern "C" void kernel_launch(void* const* d_in, const int* in_sizes, int n_in,
                              void* d_out, int out_size, void* d_ws, size_t ws_size,
                              hipStream_t stream) {
    const float* values  = (const float*)d_in[0];
    const float* keys    = (const float*)d_in[1];
    const float* queries = (const float*)d_in[2];
    const float* Wv      = (const float*)d_in[3];
    const float* Wk      = (const float*)d_in[4];
    const float* Wq      = (const float*)d_in[5];
    float* out = (float*)d_out;

    short* qb = (short*)d_ws;         // [b][s][e] bf16, 8MB
    short* kb = qb + XE;              // [b][s][e] bf16, 8MB
    short* vt = kb + XE;              // [b][d][s] bf16 (V^T), 8MB
    float* op1 = (float*)(vt + XE);   // split-1 O partial, fp32, 16MB
    float* lp  = op1 + XE;            // l partials: 2 x [b*NH+h][q], 0.5MB

    proj_f32<<<768, 256, 0, stream>>>(queries, keys, values, Wq, Wk, Wv,
                                      qb, kb, vt);

    const size_t need = 3 * XE * sizeof(short) + XE * sizeof(float)
                      + (size_t)2 * 2 * NH * SEQ * sizeof(float);  // ~40.5MB
    if (ws_size >= need) {
        attn_mfma<2><<<1024, 256, 0, stream>>>(qb, kb, vt, out, op1, lp);
        merge_split<<<2048, 256, 0, stream>>>(out, op1, lp);
    } else {
        attn_mfma<1><<<512, 256, 0, stream>>>(qb, kb, vt, out, nullptr, nullptr);
    }
}

// Round 6
// 212.824 us; speedup vs baseline: 1.1049x; 1.1049x over previous
//
#include <hip/hip_runtime.h>
#include <math.h>

#define SEQ 2048
#define EMB 1024
#define NH  16
#define HD  64

typedef __attribute__((ext_vector_type(8))) short short8;   // 8 bf16 = 4 VGPRs
typedef __attribute__((ext_vector_type(4))) float f32x4;    // MFMA acc

static const size_t XE = (size_t)2 * SEQ * EMB;  // 4,194,304 elems
static const size_t WE = (size_t)EMB * EMB;      // 1,048,576 elems

// RNE float -> bf16 bits (inputs finite)
static __device__ __forceinline__ short f2bf(float f) {
    unsigned u = __builtin_bit_cast(unsigned, f);
    u = u + 0x7fffu + ((u >> 16) & 1u);
    return (short)(u >> 16);
}

// packed 2x f32 -> 2x bf16 (low = a, high = b)
#if __has_builtin(__builtin_amdgcn_cvt_pk_bf16_f32)
typedef __attribute__((ext_vector_type(2))) __bf16 bf16x2;
static __device__ __forceinline__ unsigned pk2(float a, float b) {
    bf16x2 v = __builtin_amdgcn_cvt_pk_bf16_f32(a, b);
    return __builtin_bit_cast(unsigned, v);
}
#else
static __device__ __forceinline__ unsigned pk2(float a, float b) {
    return (unsigned)(unsigned short)f2bf(a) |
           ((unsigned)(unsigned short)f2bf(b) << 16);
}
#endif

static __device__ __forceinline__ short8 cvt8(float4 a, float4 b) {
    union { unsigned u[4]; short8 s; } r;
    r.u[0] = pk2(a.x, a.y); r.u[1] = pk2(a.z, a.w);
    r.u[2] = pk2(b.x, b.y); r.u[3] = pk2(b.z, b.w);
    return r.s;
}

// async global->LDS, 16B/lane; LDS dest = wave-uniform base + lane*16
static __device__ __forceinline__ void gload16(const void* g, void* l) {
    __builtin_amdgcn_global_load_lds(
        (const __attribute__((address_space(1))) void*)g,
        (__attribute__((address_space(3))) void*)l, 16, 0, 0);
}

// ---------------------------------------------------------------------------
// Convert the three small weight matrices to bf16 (12 MB read, 6 MB write).
// Layout in dst: [Wq | Wk | Wv], WE elems each.
// ---------------------------------------------------------------------------
__global__ __launch_bounds__(256)
void cvt_w(const float* __restrict__ s0, const float* __restrict__ s1,
           const float* __restrict__ s2, short* __restrict__ d) {
    int id = blockIdx.x;                 // 0..1535
    int seg = id >> 9, off = id & 511;
    const float* s = (seg == 0) ? s0 : (seg == 1) ? s1 : s2;
    short* dd = d + (size_t)seg * WE;
    size_t i = (size_t)off * 256 + threadIdx.x;
    const float4* sp = (const float4*)s;
    float4 a = sp[2 * i], b = sp[2 * i + 1];
    *(short8*)(dd + i * 8) = cvt8(a, b);
}

// ---------------------------------------------------------------------------
// Projection GEMM. The BIG operand (X: queries/keys/values, fp32) is staged
// DIRECTLY via global_load_lds into fp32 LDS (no VGPR round-trip) with an
// XOR chunk swizzle (chunk ^= row&7) so fragment reads are 2-way/bank (free).
// fp32->bf16 happens at fragment-read time (2x ds_read_b128 + 4 pk2).
// The small operand (W, bf16 pre-converted) is staged bf16 m97-style.
// Tile 128x128, BK=32, 256 thr, single-barrier double-buffer.
// z=0: qb = Q@Wq^T. z=1: kbuf. z=2: operands swap (A=Wv, B=values) so the
// output is V^T (vt[b][d][s]) with coalesced stores.
// XCD swizzle: each XCD owns 4 X-strips; the 8 opposing tiles cycle inner.
// ---------------------------------------------------------------------------
__global__ __launch_bounds__(256, 3)
void proj(const float* __restrict__ Xq, const float* __restrict__ Xk,
          const float* __restrict__ Xv, const short* __restrict__ Wb,
          short* __restrict__ qb, short* __restrict__ kbuf,
          short* __restrict__ vt) {
    __shared__ float4 Fs[2][1024];   // fp32 operand tiles (128x32), 32 KB
    __shared__ short8 Hs[2][512];    // bf16 operand tiles (128x32), 16 KB

    const int L = blockIdx.x;
    const int xcd = L & 7, i = L >> 3;   // i 0..95
    const int z = i >> 5;                // 0..2
    const int m = i & 31;
    const int ty = xcd * 4 + (m & 3);    // 0..31  (32-tile operand strip)
    const int tx = m >> 2;               // 0..7   (8-tile operand strip)

    const float* Fop; const short* Hop; short* C;
    if (z == 0)      { Fop = Xq; Hop = Wb;           C = qb;   }
    else if (z == 1) { Fop = Xk; Hop = Wb + WE;      C = kbuf; }
    else             { Fop = Xv; Hop = Wb + 2 * WE;  C = vt;   }
    const int fr0 = ty * 128;   // F-operand rows (X side, 4096 rows)
    const int hr0 = tx * 128;   // H-operand rows (W side, 1024 rows)

    const int t = threadIdx.x, w = t >> 6, lane = t & 63;
    const int l15 = lane & 15, quad = lane >> 4;
    const int mh = (w >> 1) * 64, nh2 = (w & 1) * 64;

    // -------- staging (fire-and-forget) --------
    // F: 128x32 fp32 = 1024 16B-chunks; slot (row, c) holds global chunk
    //    c^(row&7). 4 calls/thread.
    // H: 128x32 bf16 = 512 chunks, slot = c*128+row. 2 calls/thread.
    auto stageF = [&](int p, int k0) {
#pragma unroll
        for (int j = 0; j < 4; ++j) {
            int g = j * 256 + t, row = g >> 3, c = g & 7;
            int cs = c ^ (row & 7);
            gload16(Fop + (size_t)(fr0 + row) * EMB + k0 + cs * 4,
                    &Fs[p][j * 256 + w * 64]);
        }
    };
    auto stageH = [&](int p, int k0) {
#pragma unroll
        for (int j = 0; j < 2; ++j) {
            int g = j * 256 + t, row = g & 127, c = g >> 7;
            gload16(Hop + (size_t)(hr0 + row) * EMB + k0 + c * 8,
                    &Hs[p][j * 256 + w * 64]);
        }
    };
    // fp32 fragment read + convert: row fr (0..127), k = quad*8..quad*8+7
    auto fragF = [&](int p, int fr) -> short8 {
        int r7 = fr & 7;
        float4 a = Fs[p][fr * 8 + ((2 * quad) ^ r7)];
        float4 b = Fs[p][fr * 8 + ((2 * quad + 1) ^ r7)];
        return cvt8(a, b);
    };

    f32x4 acc[4][4];
#pragma unroll
    for (int a = 0; a < 4; ++a)
#pragma unroll
        for (int b = 0; b < 4; ++b) acc[a][b] = 0.f;

    stageF(0, 0);
    stageH(0, 0);

    int p = 0;
    for (int k0 = 0; k0 < EMB; k0 += 32, p ^= 1) {
        __syncthreads();   // drains buf-p loads (issued one full iter ago)
        if (k0 + 32 < EMB) { stageF(p ^ 1, k0 + 32); stageH(p ^ 1, k0 + 32); }

        short8 af[4], bf[4];
        if (z < 2) {   // A = X (fp32 path), B = W (bf16 path)
#pragma unroll
            for (int mi = 0; mi < 4; ++mi)
                af[mi] = fragF(p, mh + mi * 16 + l15);
#pragma unroll
            for (int ni = 0; ni < 4; ++ni)
                bf[ni] = Hs[p][quad * 128 + nh2 + ni * 16 + l15];
        } else {       // A = Wv (bf16 path), B = values (fp32 path)
#pragma unroll
            for (int mi = 0; mi < 4; ++mi)
                af[mi] = Hs[p][quad * 128 + mh + mi * 16 + l15];
#pragma unroll
            for (int ni = 0; ni < 4; ++ni)
                bf[ni] = fragF(p, nh2 + ni * 16 + l15);
        }
#pragma unroll
        for (int mi = 0; mi < 4; ++mi)
#pragma unroll
            for (int ni = 0; ni < 4; ++ni)
                acc[mi][ni] = __builtin_amdgcn_mfma_f32_16x16x32_bf16(
                    af[mi], bf[ni], acc[mi][ni], 0, 0, 0);
    }

    // epilogue: gm = A-row, gn = B-row
    const int am0 = (z < 2) ? fr0 : hr0;
    const int bn0 = (z < 2) ? hr0 : fr0;
#pragma unroll
    for (int mi = 0; mi < 4; ++mi)
#pragma unroll
        for (int ni = 0; ni < 4; ++ni)
#pragma unroll
            for (int r = 0; r < 4; ++r) {
                int gm = am0 + mh + mi * 16 + quad * 4 + r;
                int gn = bn0 + nh2 + ni * 16 + l15;
                short v = f2bf(acc[mi][ni][r]);
                if (z < 2) {
                    C[(size_t)gm * EMB + gn] = v;             // [m][n]
                } else {  // gm = d, gn = b*2048+s -> vt[b][d][s]
                    C[((size_t)(gn >> 11) * EMB + gm) * SEQ + (gn & 2047)] = v;
                }
            }
}

// ---------------------------------------------------------------------------
// Flash attention, bf16 MFMA, fixed-max softmax, S^T trick (A=K, B=Q) for
// packed b64 P-writes. XCD swizzle; K/V double-buffer, one barrier/tile.
// P reuses the dead Qs LDS (Q hoisted to regs) -> 48 KB -> 3 blocks/CU.
// (round-4 structure, 71 us, + LDS reuse; split-K reverted)
// ---------------------------------------------------------------------------
__global__ __launch_bounds__(256, 3)
void attn_mfma(const short* __restrict__ Qg, const short* __restrict__ Kg,
               const short* __restrict__ Vtg, float* __restrict__ OutD) {
    __shared__ short8 QPs[1024];    // Q [dchunk(8)][qrow(128)], then P; 16KB
    __shared__ short8 Ks[2][512];   // dbuf [dchunk(8)][krow(64)] 16KB
    __shared__ short8 Vs[2][512];   // dbuf [kchunk(8)][d(64)]    16KB

    const int t = threadIdx.x, w = t >> 6, lane = t & 63;
    const int l15 = lane & 15, quad = lane >> 4;
    const int L = blockIdx.x;
    const int xcd = L & 7, i = L >> 3;        // i 0..63
    const int bh = xcd * 4 + (i & 3);         // 0..31
    const int q0 = (i >> 2) * 128;            // 16 q-tiles
    const int b = bh >> 4, h = bh & 15;
    const short* Qb = Qg + (size_t)b * SEQ * EMB + h * HD;
    const short* Kb = Kg + (size_t)b * SEQ * EMB + h * HD;
    const short* Vb = Vtg + ((size_t)b * EMB + h * HD) * SEQ;

    // prologue: stage Q tile + K/V tile0
#pragma unroll
    for (int j2 = 0; j2 < 4; ++j2) {
        int g = w * 4 + j2, c = g >> 1, row = (g & 1) * 64 + lane;
        gload16(Qb + (size_t)(q0 + row) * EMB + c * 8, &QPs[g * 64]);
    }
#pragma unroll
    for (int j2 = 0; j2 < 2; ++j2) {
        int c = w * 2 + j2;
        gload16(Kb + (size_t)lane * EMB + c * 8, &Ks[0][c * 64]);
        gload16(Vb + (size_t)lane * SEQ + c * 8, &Vs[0][c * 64]);
    }
    __syncthreads();   // drains prologue loads

    // hoist Q fragments (B-operand, lane l15 = q); QPs then dead -> P buffer
    short8 qf[2][2];
#pragma unroll
    for (int qi = 0; qi < 2; ++qi)
#pragma unroll
        for (int kb2 = 0; kb2 < 2; ++kb2)
            qf[qi][kb2] = QPs[(kb2 * 4 + quad) * 128 + w * 32 + qi * 16 + l15];
    __syncthreads();   // all hoists done before P overwrites QPs

    f32x4 o[2][4];
    float lr[2] = {0.f, 0.f};
#pragma unroll
    for (int qi = 0; qi < 2; ++qi)
#pragma unroll
        for (int ni = 0; ni < 4; ++ni) o[qi][ni] = 0.f;
    const float cl2 = 0.18033688011112042f;   // (1/8) * log2(e)
    const float c0  = 11.541560327111707f;    // 64 * cl2

    int p = 0;
    for (int kt = 0; kt < SEQ; kt += 64, p ^= 1) {
        if (kt) __syncthreads();   // drains buf-p loads (issued last iter)
        if (kt + 64 < SEQ) {
#pragma unroll
            for (int j2 = 0; j2 < 2; ++j2) {
                int c = w * 2 + j2;
                gload16(Kb + (size_t)(kt + 64 + lane) * EMB + c * 8,
                        &Ks[p ^ 1][c * 64]);
                gload16(Vb + (size_t)lane * SEQ + kt + 64 + c * 8,
                        &Vs[p ^ 1][c * 64]);
            }
        }

        // ---- T = K Q^T : rows = key, cols = q ----
        f32x4 s[4][2];
#pragma unroll
        for (int kblk = 0; kblk < 4; ++kblk)
#pragma unroll
            for (int qi = 0; qi < 2; ++qi) s[kblk][qi] = 0.f;
#pragma unroll
        for (int kb2 = 0; kb2 < 2; ++kb2) {
            short8 ak[4];
#pragma unroll
            for (int kblk = 0; kblk < 4; ++kblk)
                ak[kblk] = Ks[p][(kb2 * 4 + quad) * 64 + kblk * 16 + l15];
#pragma unroll
            for (int kblk = 0; kblk < 4; ++kblk)
#pragma unroll
                for (int qi = 0; qi < 2; ++qi)
                    s[kblk][qi] = __builtin_amdgcn_mfma_f32_16x16x32_bf16(
                        ak[kblk], qf[qi][kb2], s[kblk][qi], 0, 0, 0);
        }

        // ---- fixed-max softmax + packed b64 P write (into QPs) ----
#pragma unroll
        for (int qi = 0; qi < 2; ++qi) {
            int row = w * 32 + qi * 16 + l15;
#pragma unroll
            for (int kblk = 0; kblk < 4; ++kblk) {
                float p0 = __builtin_amdgcn_exp2f(fmaf(s[kblk][qi][0], cl2, -c0));
                float p1 = __builtin_amdgcn_exp2f(fmaf(s[kblk][qi][1], cl2, -c0));
                float p2 = __builtin_amdgcn_exp2f(fmaf(s[kblk][qi][2], cl2, -c0));
                float p3 = __builtin_amdgcn_exp2f(fmaf(s[kblk][qi][3], cl2, -c0));
                lr[qi] += (p0 + p1) + (p2 + p3);
                uint2 pv; pv.x = pk2(p0, p1); pv.y = pk2(p2, p3);
                int chunk = kblk * 2 + (quad >> 1);
                *(uint2*)((char*)QPs +
                          (((chunk * 128 + row) << 4) | ((quad & 1) << 3))) = pv;
            }
        }
        // no barrier: each wave reads back only its own q rows (w-partitioned)

        // ---- O += P V ----
#pragma unroll
        for (int kb2 = 0; kb2 < 2; ++kb2) {
            short8 ap[2], bv[4];
#pragma unroll
            for (int qi = 0; qi < 2; ++qi)
                ap[qi] = QPs[(kb2 * 4 + quad) * 128 + w * 32 + qi * 16 + l15];
#pragma unroll
            for (int ni = 0; ni < 4; ++ni)
                bv[ni] = Vs[p][(kb2 * 4 + quad) * 64 + ni * 16 + l15];
#pragma unroll
            for (int qi = 0; qi < 2; ++qi)
#pragma unroll
                for (int ni = 0; ni < 4; ++ni)
                    o[qi][ni] = __builtin_amdgcn_mfma_f32_16x16x32_bf16(
                        ap[qi], bv[ni], o[qi][ni], 0, 0, 0);
        }
    }

    // ---- epilogue: reduce l across quads, normalize, store fp32 ----
#pragma unroll
    for (int qi = 0; qi < 2; ++qi) {
        float l = lr[qi];
        l += __shfl_xor(l, 16);
        l += __shfl_xor(l, 32);
        lr[qi] = l;
    }
#pragma unroll
    for (int qi = 0; qi < 2; ++qi)
#pragma unroll
        for (int r = 0; r < 4; ++r) {
            float inv = 1.0f / __shfl(lr[qi], quad * 4 + r);
            int q = q0 + w * 32 + qi * 16 + quad * 4 + r;
            float* op = OutD + ((size_t)b * SEQ + q) * EMB + h * HD;
#pragma unroll
            for (int ni = 0; ni < 4; ++ni)
                op[ni * 16 + l15] = o[qi][ni][r] * inv;
        }
}

// ---------------------------------------------------------------------------
extern "C" void kernel_launch(void* const* d_in, const int* in_sizes, int n_in,
                              void* d_out, int out_size, void* d_ws, size_t ws_size,
                              hipStream_t stream) {
    const float* values  = (const float*)d_in[0];
    const float* keys    = (const float*)d_in[1];
    const float* queries = (const float*)d_in[2];
    const float* Wv      = (const float*)d_in[3];
    const float* Wk      = (const float*)d_in[4];
    const float* Wq      = (const float*)d_in[5];
    float* out = (float*)d_out;

    // ws: qb, kb (8MB each), vt (8MB), wb = [Wq|Wk|Wv] bf16 (6MB) = 30MB
    // (round-1 successfully used 48MB of ws, so this fits)
    short* qb = (short*)d_ws;
    short* kb = qb + XE;
    short* vt = kb + XE;
    short* wb = vt + XE;

    cvt_w<<<1536, 256, 0, stream>>>(Wq, Wk, Wv, wb);
    proj<<<768, 256, 0, stream>>>(queries, keys, values, wb, qb, kb, vt);
    attn_mfma<<<512, 256, 0, stream>>>(qb, kb, vt, out);
}